// Round 12
// baseline (2544.127 us; speedup 1.0000x reference)
//
#include <hip/hip_runtime.h>
#include <hip/hip_bf16.h>
#include <cstdint>

#define TN 8192
#define DN 1024
#define HN 4096
#define EN 8
#define PADMAX 18432  // >= 16384 + 8*127 worst-case pad(128), rounded up

typedef __attribute__((ext_vector_type(8))) short short8;
typedef __attribute__((ext_vector_type(4))) float f32x4;
typedef __attribute__((ext_vector_type(4))) unsigned short ushort4v;

__device__ inline unsigned short f2bf(float f) {
  unsigned u = __builtin_bit_cast(unsigned, f);
  u = u + 0x7fffu + ((u >> 16) & 1u);
  return (unsigned short)(u >> 16);
}
__device__ inline float bf2f(unsigned short u) {
  unsigned v = ((unsigned)u) << 16;
  return __builtin_bit_cast(float, v);
}

// exact tanh-GELU identity: 0.5*v*(1+tanh(z)) == v * sigmoid(2z)
__device__ inline float gelu_f(float v) {
  float z2 = 1.5957691216057308f * (v + 0.044715f * v * v * v);
  return v / (1.f + __expf(-z2));
}

__device__ inline void gload_lds16(const void* g, void* l) {
  __builtin_amdgcn_global_load_lds(
      (const __attribute__((address_space(1))) unsigned int*)g,
      (__attribute__((address_space(3))) unsigned int*)l, 16, 0, 0);
}

// prep: blocks [0,2048) = atomic-free router; rest = grid-stride bf16 cvt
__global__ __launch_bounds__(256) void prep_k(const float* __restrict__ x,
                                              const float* __restrict__ rw,
                                              const float* __restrict__ w1,
                                              const float* __restrict__ w2,
                                              unsigned short* __restrict__ xb,
                                              unsigned short* __restrict__ w1b,
                                              unsigned short* __restrict__ w2b,
                                              int* __restrict__ eids,
                                              float* __restrict__ wts,
                                              int nCvtBlk, long nGroups) {
  if (blockIdx.x < TN / 4) {
    int wid = threadIdx.x >> 6, lane = threadIdx.x & 63;
    int t = blockIdx.x * 4 + wid;
    const float* xr = x + (long)t * DN;
    float a[EN];
#pragma unroll
    for (int e = 0; e < EN; ++e) a[e] = 0.f;
    for (int k = lane; k < DN; k += 64) {
      float xv = xr[k];
#pragma unroll
      for (int e = 0; e < EN; ++e) a[e] += xv * rw[e * DN + k];
    }
#pragma unroll
    for (int off = 32; off > 0; off >>= 1) {
#pragma unroll
      for (int e = 0; e < EN; ++e) a[e] += __shfl_xor(a[e], off);
    }
    if (lane == 0) {
      float mx = a[0];
#pragma unroll
      for (int e = 1; e < EN; ++e) mx = fmaxf(mx, a[e]);
      float p[EN], s = 0.f;
#pragma unroll
      for (int e = 0; e < EN; ++e) { p[e] = __expf(a[e] - mx); s += p[e]; }
      int e0 = 0; float b0 = p[0];
#pragma unroll
      for (int e = 1; e < EN; ++e) if (p[e] > b0) { b0 = p[e]; e0 = e; }
      int e1 = -1; float b1 = -1.f;
#pragma unroll
      for (int e = 0; e < EN; ++e) if (e != e0 && p[e] > b1) { b1 = p[e]; e1 = e; }
      float inv = 1.f / s;
      eids[2 * t] = e0; eids[2 * t + 1] = e1;
      wts[2 * t] = b0 * inv; wts[2 * t + 1] = b1 * inv;
    }
  } else {
    const long GX = (long)TN * DN / 8;
    const long GW = (long)EN * HN * DN / 8;
    long g = (long)(blockIdx.x - TN / 4) * 256 + threadIdx.x;
    long stride = (long)nCvtBlk * 256;
    for (; g < nGroups; g += stride) {
      const float* s; unsigned short* d; long j;
      if (g < GX) { s = x; d = xb; j = g; }
      else if (g < GX + GW) { s = w1; d = w1b; j = g - GX; }
      else { s = w2; d = w2b; j = g - GX - GW; }
      long e8 = j * 8;
      float4 v0 = *(const float4*)(s + e8);
      float4 v1 = *(const float4*)(s + e8 + 4);
      short8 pk;
      pk[0] = (short)f2bf(v0.x); pk[1] = (short)f2bf(v0.y);
      pk[2] = (short)f2bf(v0.z); pk[3] = (short)f2bf(v0.w);
      pk[4] = (short)f2bf(v1.x); pk[5] = (short)f2bf(v1.y);
      pk[6] = (short)f2bf(v1.z); pk[7] = (short)f2bf(v1.w);
      *(short8*)(d + e8) = pk;
    }
  }
}

// single block: register histogram -> wave reduce -> LDS combine -> poff prefix
__global__ __launch_bounds__(1024) void count_k(const int* __restrict__ eids,
                                                int* __restrict__ poff) {
  __shared__ int hist[16][EN];
  int tid = threadIdx.x, lane = tid & 63, w = tid >> 6;
  int c[EN];
#pragma unroll
  for (int e = 0; e < EN; ++e) c[e] = 0;
  for (int i = tid; i < 2 * TN; i += 1024) {
    int e = eids[i];
#pragma unroll
    for (int j = 0; j < EN; ++j) c[j] += (e == j) ? 1 : 0;
  }
#pragma unroll
  for (int j = 0; j < EN; ++j) {
#pragma unroll
    for (int off = 32; off > 0; off >>= 1) c[j] += __shfl_xor(c[j], off);
  }
  if (lane == 0) {
#pragma unroll
    for (int j = 0; j < EN; ++j) hist[w][j] = c[j];
  }
  __syncthreads();
  if (tid == 0) {
    int o = 0;
    for (int e = 0; e < EN; ++e) {
      int s = 0;
      for (int ww = 0; ww < 16; ++ww) s += hist[ww][e];
      poff[e] = o;
      o += (s + 127) & ~127;
    }
    poff[EN] = o;
  }
}

__global__ __launch_bounds__(256) void scatter_k(const int* __restrict__ eids,
                                                 const float* __restrict__ wts,
                                                 const int* __restrict__ poff,
                                                 int* __restrict__ cursor,
                                                 int* __restrict__ pairTok,
                                                 float* __restrict__ pairW,
                                                 int* __restrict__ slotPos) {
  int t = blockIdx.x * 256 + threadIdx.x;
#pragma unroll
  for (int k = 0; k < 2; ++k) {
    int e = eids[2 * t + k];
    int p = atomicAdd(&cursor[e], 1);
    int pos = poff[e] + p;
    pairTok[pos] = t;
    pairW[pos] = wts[2 * t + k];
    slotPos[2 * t + k] = pos;
  }
}

// out[t] = w0 * yb[pos0] + w1 * yb[pos1]
__global__ __launch_bounds__(256) void combine_k(const unsigned short* __restrict__ yb,
                                                 const float* __restrict__ wts,
                                                 const int* __restrict__ slotPos,
                                                 float* __restrict__ out) {
  int t = blockIdx.x;
  int p0 = slotPos[2 * t], p1 = slotPos[2 * t + 1];
  float w0 = wts[2 * t], w1 = wts[2 * t + 1];
  int c = threadIdx.x * 4;
  ushort4v y0 = *(const ushort4v*)(yb + (long)p0 * DN + c);
  ushort4v y1 = *(const ushort4v*)(yb + (long)p1 * DN + c);
  float4 o;
  o.x = w0 * bf2f(y0.x) + w1 * bf2f(y1.x);
  o.y = w0 * bf2f(y0.y) + w1 * bf2f(y1.y);
  o.z = w0 * bf2f(y0.z) + w1 * bf2f(y1.z);
  o.w = w0 * bf2f(y0.w) + w1 * bf2f(y1.w);
  *(float4*)(out + (long)t * DN + c) = o;
}

// ---- 128x128 GEMM, BK=32, 4 waves (2x2), 32 KiB LDS dbuf -> 5 blocks/CU ----
// R12: occupancy 2->5 blocks/CU (m114 co-scheduling absorbs barrier drains).
// LDS: A[P] at P*8192, B[P] at 16384+P*8192. Row = 32 bf16 = 4 slots of 16B.
// Swizzle: slot ^ ((row>>1)&3) (2-way residual conflict = free, m136).
// Per K-step: 8 ds_read_b128, 16 MFMA, stage 4 gload_lds into dead buf,
// counted vmcnt(4), 2 barriers.

#define BAR() { asm volatile("" ::: "memory"); __builtin_amdgcn_s_barrier(); \
                asm volatile("" ::: "memory"); }
#define LGKM0() { asm volatile("s_waitcnt lgkmcnt(0)" ::: "memory"); }

#define LDA4(PAR) { const char* _b = smem + (PAR)*8192;                              \
  _Pragma("unroll") for (int m = 0; m < 4; ++m) {                                    \
    int row = waveM*64 + m*16 + (lane & 15);                                         \
    a[m] = *(const short8*)(_b + row*64 + (((lane>>4) ^ ((row>>1)&3)) * 16)); } }

#define LDB4(PAR) { const char* _b = smem + 16384 + (PAR)*8192;                      \
  _Pragma("unroll") for (int n = 0; n < 4; ++n) {                                    \
    int row = waveN*64 + n*16 + (lane & 15);                                         \
    b[n] = *(const short8*)(_b + row*64 + (((lane>>4) ^ ((row>>1)&3)) * 16)); } }

#define MM16() { __builtin_amdgcn_s_setprio(1);                                      \
  _Pragma("unroll") for (int m = 0; m < 4; ++m)                                      \
    _Pragma("unroll") for (int n = 0; n < 4; ++n)                                    \
      acc[m][n] = __builtin_amdgcn_mfma_f32_16x16x32_bf16(a[m], b[n], acc[m][n], 0, 0, 0); \
  __builtin_amdgcn_s_setprio(0); }

template <int MODE, bool BBF16>
__global__ __launch_bounds__(256, 5) void moe_gemm128_k(
    const unsigned short* __restrict__ Ab, const void* __restrict__ Bsrc,
    void* __restrict__ OutP, const int* __restrict__ pairTok,
    const float* __restrict__ pairW, const int* __restrict__ poff, int chunkStart) {
  constexpr int KD = (MODE == 1) ? DN : HN;
  constexpr int ND = (MODE == 1) ? HN : DN;
  constexpr int SPLIT = (MODE == 3) ? 2 : 1;
  constexpr int KLEN = KD / SPLIT;
  constexpr int NT = KLEN / 32;

  extern __shared__ char smem[];

  int NX = gridDim.x;
  int NXY = NX * gridDim.y;
  int orig = blockIdx.y * NX + blockIdx.x;
  int qq = NXY >> 3, rrm = NXY & 7;
  int xcd = orig & 7, pos = orig >> 3;
  int wg = (xcd < rrm ? xcd * (qq + 1) : rrm * (qq + 1) + (xcd - rrm) * qq) + pos;

  int NYt = NXY / NX;
  const int GH = 8;
  int npg = GH * NX;
  int gid = wg / npg;
  int rem = wg - gid * npg;
  int rowsLeft = NYt - gid * GH;
  int gh = rowsLeft < GH ? rowsLeft : GH;
  int row = gid * GH + rem % gh;
  int col = rem / gh;
  int tileN = col * 128;
  int tileStart = chunkStart + row * 128;

  int Ppad = poff[EN];
  if (tileStart >= Ppad) return;
  int e = 0;
  while (e < EN - 1 && tileStart >= poff[e + 1]) ++e;

  int tid = threadIdx.x;
  int wid = tid >> 6, lane = tid & 63;
  int waveM = wid >> 1, waveN = wid & 1;
  int kbase = (MODE == 3) ? blockIdx.z * KLEN : 0;

  // staging: thread covers groups q=tid (row tid>>2) and q=256+tid (row 64+tid>>2)
  // linear slot q&3; global slot s = (q&3) ^ ((row>>1)&3); s same for both rows.
  int r0 = tid >> 2;
  int s0 = (tid & 3) ^ ((tid >> 3) & 3);
  const char* aSrc[2];
  const char* bSrc[2];
#pragma unroll
  for (int j = 0; j < 2; ++j) {
    int rw_ = j * 64 + r0;
    long abase;
    if (MODE == 1) {
      int tok = pairTok[tileStart + rw_];
      if (tok < 0) tok = 0;  // padding row: load token 0, result never read
      abase = (long)tok * KD;
    } else {
      abase = (long)(tileStart - chunkStart + rw_) * KD;
    }
    aSrc[j] = (const char*)(Ab + abase + kbase + s0 * 8);
    long bb = (long)e * ND * KD + (long)(tileN + rw_) * KD + kbase + s0 * 8;
    bSrc[j] = (const char*)Bsrc + bb * (BBF16 ? 2 : 4);
  }

  auto stageA = [&](int k0, int par) {
#pragma unroll
    for (int j = 0; j < 2; ++j)
      gload_lds16(aSrc[j] + (long)k0 * 2, smem + par * 8192 + (j * 256 + tid) * 16);
  };
  auto stageB = [&](int k0, int par) {
    if constexpr (BBF16) {
#pragma unroll
      for (int j = 0; j < 2; ++j)
        gload_lds16(bSrc[j] + (long)k0 * 2, smem + 16384 + par * 8192 + (j * 256 + tid) * 16);
    } else {
#pragma unroll
      for (int j = 0; j < 2; ++j) {
        const float4* pf = (const float4*)(bSrc[j] + (long)k0 * 4);
        float4 v0 = pf[0], v1 = pf[1];
        short8 pk;
        pk[0] = (short)f2bf(v0.x); pk[1] = (short)f2bf(v0.y);
        pk[2] = (short)f2bf(v0.z); pk[3] = (short)f2bf(v0.w);
        pk[4] = (short)f2bf(v1.x); pk[5] = (short)f2bf(v1.y);
        pk[6] = (short)f2bf(v1.z); pk[7] = (short)f2bf(v1.w);
        *(short8*)(smem + 16384 + par * 8192 + (j * 256 + tid) * 16) = pk;
      }
    }
  };

  f32x4 acc[4][4];
#pragma unroll
  for (int m = 0; m < 4; ++m)
#pragma unroll
    for (int n = 0; n < 4; ++n) acc[m][n] = (f32x4){0.f, 0.f, 0.f, 0.f};
  short8 a[4], b[4];

  // prologue: tile0 -> buf0, tile1 -> buf1 (8 loads); keep tile1's 4 in flight
  stageA(0, 0); stageB(0, 0);
  stageA(32, 1); stageB(32, 1);
  if constexpr (BBF16) {
    asm volatile("s_waitcnt vmcnt(4)" ::: "memory");
  } else {
    asm volatile("s_waitcnt vmcnt(0) lgkmcnt(0)" ::: "memory");
  }
  BAR();

  for (int t = 0; t < NT; ++t) {
    int P = t & 1;
    int k2 = (t + 2) * 32;
    LDA4(P); LDB4(P);
    LGKM0();        // own reads retired (data in regs)
    BAR();          // all waves' reads retired -> buf P is dead
    if (t + 2 < NT) { stageA(k2, P); stageB(k2, P); }  // refill dead buf
    MM16();
    if (BBF16 && t + 2 < NT) {
      asm volatile("s_waitcnt vmcnt(4)" ::: "memory");  // stage(t+1) landed
    } else {
      asm volatile("s_waitcnt vmcnt(0)" ::: "memory");
    }
    BAR();
  }

  if (MODE == 1) {
    unsigned short* hbp = (unsigned short*)OutP;
    int rl0 = tileStart - chunkStart + waveM * 64;
#pragma unroll
    for (int m = 0; m < 4; ++m) {
#pragma unroll
      for (int r = 0; r < 4; ++r) {
        int rl = rl0 + m * 16 + (lane >> 4) * 4 + r;
#pragma unroll
        for (int n = 0; n < 4; ++n) {
          int coln = tileN + waveN * 64 + n * 16 + (lane & 15);
          hbp[(long)rl * HN + coln] = f2bf(gelu_f(acc[m][n][r]));
        }
      }
    }
  } else if (MODE == 2) {
    unsigned short* ybp = (unsigned short*)OutP;
#pragma unroll
    for (int m = 0; m < 4; ++m) {
#pragma unroll
      for (int r = 0; r < 4; ++r) {
        int p = tileStart + waveM * 64 + m * 16 + (lane >> 4) * 4 + r;
#pragma unroll
        for (int n = 0; n < 4; ++n) {
          int coln = tileN + waveN * 64 + n * 16 + (lane & 15);
          ybp[(long)p * ND + coln] = f2bf(acc[m][n][r]);
        }
      }
    }
  } else {
    float* outF = (float*)OutP;
#pragma unroll
    for (int m = 0; m < 4; ++m) {
#pragma unroll
      for (int r = 0; r < 4; ++r) {
        int p = tileStart + waveM * 64 + m * 16 + (lane >> 4) * 4 + r;
        int tok = pairTok[p];
        if (tok < 0) continue;
        float wv = pairW[p];
#pragma unroll
        for (int n = 0; n < 4; ++n) {
          int coln = tileN + waveN * 64 + n * 16 + (lane & 15);
          atomicAdd(&outF[(long)tok * DN + coln], wv * acc[m][n][r]);
        }
      }
    }
  }
}

extern "C" void kernel_launch(void* const* d_in, const int* in_sizes, int n_in,
                              void* d_out, int out_size, void* d_ws, size_t ws_size,
                              hipStream_t stream) {
  const float* x = (const float*)d_in[0];
  const float* rw = (const float*)d_in[1];
  const float* w1 = (const float*)d_in[2];
  const float* w2 = (const float*)d_in[3];
  char* W = (char*)d_ws;
  size_t off = 0;
  auto alloc = [&](size_t sz) {
    off = (off + 255) & ~(size_t)255;
    size_t r = off; off += sz; return r;
  };
  size_t ctrlO = alloc(256);  // cursor[8], poff[9]
  size_t eidsO = alloc((size_t)TN * 2 * 4);
  size_t wtsO  = alloc((size_t)TN * 2 * 4);
  size_t ptokO = alloc((size_t)PADMAX * 4);
  size_t pwO   = alloc((size_t)PADMAX * 4);
  size_t sposO = alloc((size_t)TN * 2 * 4);
  size_t xbO   = alloc((size_t)TN * DN * 2);
  size_t wB = (size_t)EN * HN * DN * 2;
  size_t afterFixed = (off + 255) & ~(size_t)255;
  bool bw = ws_size >= afterFixed + 2 * wB + (size_t)128 * HN * 2 + 4096;
  size_t w1bO = 0, w2bO = 0;
  if (bw) { w1bO = alloc(wB); w2bO = alloc(wB); }
  size_t ybB = (size_t)PADMAX * DN * 2;
  size_t afterW = (off + 255) & ~(size_t)255;
  bool dense = ws_size >= afterW + ybB + (size_t)128 * HN * 2 + 4096;
  size_t ybO = 0;
  if (dense) ybO = alloc(ybB);
  size_t hbase = (off + 255) & ~(size_t)255;
  size_t avail = ws_size > hbase ? ws_size - hbase : (size_t)128 * HN * 2;
  long Cl = (long)(avail / ((size_t)HN * 2));
  if (Cl > PADMAX) Cl = PADMAX;
  Cl &= ~127l;
  if (Cl < 128) Cl = 128;
  int C = (int)Cl;
  size_t hbO = alloc((size_t)C * HN * 2);
  int nCh = (PADMAX + C - 1) / C;

  int* cursor = (int*)(W + ctrlO);
  int* poff = cursor + 8;
  int* eids = (int*)(W + eidsO);
  float* wts = (float*)(W + wtsO);
  int* pairTok = (int*)(W + ptokO);
  float* pairW = (float*)(W + pwO);
  int* slotPos = (int*)(W + sposO);
  unsigned short* xb = (unsigned short*)(W + xbO);
  unsigned short* hb = (unsigned short*)(W + hbO);
  unsigned short* yb = (unsigned short*)(W + ybO);

  hipFuncSetAttribute(reinterpret_cast<const void*>(moe_gemm128_k<1, true>),
                      hipFuncAttributeMaxDynamicSharedMemorySize, 32768);
  hipFuncSetAttribute(reinterpret_cast<const void*>(moe_gemm128_k<2, true>),
                      hipFuncAttributeMaxDynamicSharedMemorySize, 32768);
  hipFuncSetAttribute(reinterpret_cast<const void*>(moe_gemm128_k<3, true>),
                      hipFuncAttributeMaxDynamicSharedMemorySize, 32768);
  hipFuncSetAttribute(reinterpret_cast<const void*>(moe_gemm128_k<1, false>),
                      hipFuncAttributeMaxDynamicSharedMemorySize, 32768);
  hipFuncSetAttribute(reinterpret_cast<const void*>(moe_gemm128_k<2, false>),
                      hipFuncAttributeMaxDynamicSharedMemorySize, 32768);
  hipFuncSetAttribute(reinterpret_cast<const void*>(moe_gemm128_k<3, false>),
                      hipFuncAttributeMaxDynamicSharedMemorySize, 32768);

  hipMemsetAsync(W + ctrlO, 0, 256, stream);
  hipMemsetAsync(W + ptokO, 0xFF, (size_t)PADMAX * 4, stream);  // pairTok = -1
  if (!dense) hipMemsetAsync(d_out, 0, (size_t)TN * DN * 4, stream);

  const int nCvtBlk = 4096;
  const long GX = (long)TN * DN / 8;
  const long GW = (long)EN * HN * DN / 8;
  long nGroups = GX + (bw ? 2 * GW : 0);
  prep_k<<<TN / 4 + nCvtBlk, 256, 0, stream>>>(
      x, rw, w1, w2, xb,
      bw ? (unsigned short*)(W + w1bO) : nullptr,
      bw ? (unsigned short*)(W + w2bO) : nullptr,
      eids, wts, nCvtBlk, nGroups);
  count_k<<<1, 1024, 0, stream>>>(eids, poff);
  scatter_k<<<TN / 256, 256, 0, stream>>>(eids, wts, poff, cursor, pairTok, pairW, slotPos);

  int Ctiles = C / 128;
  for (int c = 0; c < nCh; ++c) {
    int cs = c * C;
    if (bw) {
      moe_gemm128_k<1, true><<<dim3(HN / 128, Ctiles, 1), 256, 32768, stream>>>(
          xb, W + w1bO, hb, pairTok, pairW, poff, cs);
      if (dense) {
        moe_gemm128_k<2, true><<<dim3(DN / 128, Ctiles, 1), 256, 32768, stream>>>(
            hb, W + w2bO, yb, pairTok, pairW, poff, cs);
      } else {
        moe_gemm128_k<3, true><<<dim3(DN / 128, Ctiles, 2), 256, 32768, stream>>>(
            hb, W + w2bO, d_out, pairTok, pairW, poff, cs);
      }
    } else {
      moe_gemm128_k<1, false><<<dim3(HN / 128, Ctiles, 1), 256, 32768, stream>>>(
          xb, w1, hb, pairTok, pairW, poff, cs);
      if (dense) {
        moe_gemm128_k<2, false><<<dim3(DN / 128, Ctiles, 1), 256, 32768, stream>>>(
            hb, w2, yb, pairTok, pairW, poff, cs);
      } else {
        moe_gemm128_k<3, false><<<dim3(DN / 128, Ctiles, 2), 256, 32768, stream>>>(
            hb, w2, d_out, pairTok, pairW, poff, cs);
      }
    }
  }
  if (dense) {
    combine_k<<<TN, 256, 0, stream>>>(yb, wts, slotPos, (float*)d_out);
  }
}

// Round 13
// 595.552 us; speedup vs baseline: 4.2719x; 4.2719x over previous
//
#include <hip/hip_runtime.h>
#include <hip/hip_bf16.h>
#include <cstdint>

#define TN 8192
#define DN 1024
#define HN 4096
#define EN 8
#define PADMAX 18432  // >= 16384 + 8*127 worst-case pad(128), rounded up

typedef __attribute__((ext_vector_type(8))) short short8;
typedef __attribute__((ext_vector_type(4))) float f32x4;
typedef __attribute__((ext_vector_type(4))) unsigned short ushort4v;

__device__ inline unsigned short f2bf(float f) {
  unsigned u = __builtin_bit_cast(unsigned, f);
  u = u + 0x7fffu + ((u >> 16) & 1u);
  return (unsigned short)(u >> 16);
}
__device__ inline float bf2f(unsigned short u) {
  unsigned v = ((unsigned)u) << 16;
  return __builtin_bit_cast(float, v);
}

// exact tanh-GELU identity: 0.5*v*(1+tanh(z)) == v * sigmoid(2z)
__device__ inline float gelu_f(float v) {
  float z2 = 1.5957691216057308f * (v + 0.044715f * v * v * v);
  return v / (1.f + __expf(-z2));
}

__device__ inline void gload_lds16(const void* g, void* l) {
  __builtin_amdgcn_global_load_lds(
      (const __attribute__((address_space(1))) unsigned int*)g,
      (__attribute__((address_space(3))) unsigned int*)l, 16, 0, 0);
}

// prep: blocks [0,2048) = atomic-free router; rest = grid-stride bf16 cvt
__global__ __launch_bounds__(256) void prep_k(const float* __restrict__ x,
                                              const float* __restrict__ rw,
                                              const float* __restrict__ w1,
                                              const float* __restrict__ w2,
                                              unsigned short* __restrict__ xb,
                                              unsigned short* __restrict__ w1b,
                                              unsigned short* __restrict__ w2b,
                                              int* __restrict__ eids,
                                              float* __restrict__ wts,
                                              int nCvtBlk, long nGroups) {
  if (blockIdx.x < TN / 4) {
    int wid = threadIdx.x >> 6, lane = threadIdx.x & 63;
    int t = blockIdx.x * 4 + wid;
    const float* xr = x + (long)t * DN;
    float a[EN];
#pragma unroll
    for (int e = 0; e < EN; ++e) a[e] = 0.f;
    for (int k = lane; k < DN; k += 64) {
      float xv = xr[k];
#pragma unroll
      for (int e = 0; e < EN; ++e) a[e] += xv * rw[e * DN + k];
    }
#pragma unroll
    for (int off = 32; off > 0; off >>= 1) {
#pragma unroll
      for (int e = 0; e < EN; ++e) a[e] += __shfl_xor(a[e], off);
    }
    if (lane == 0) {
      float mx = a[0];
#pragma unroll
      for (int e = 1; e < EN; ++e) mx = fmaxf(mx, a[e]);
      float p[EN], s = 0.f;
#pragma unroll
      for (int e = 0; e < EN; ++e) { p[e] = __expf(a[e] - mx); s += p[e]; }
      int e0 = 0; float b0 = p[0];
#pragma unroll
      for (int e = 1; e < EN; ++e) if (p[e] > b0) { b0 = p[e]; e0 = e; }
      int e1 = -1; float b1 = -1.f;
#pragma unroll
      for (int e = 0; e < EN; ++e) if (e != e0 && p[e] > b1) { b1 = p[e]; e1 = e; }
      float inv = 1.f / s;
      eids[2 * t] = e0; eids[2 * t + 1] = e1;
      wts[2 * t] = b0 * inv; wts[2 * t + 1] = b1 * inv;
    }
  } else {
    const long GX = (long)TN * DN / 8;
    const long GW = (long)EN * HN * DN / 8;
    long g = (long)(blockIdx.x - TN / 4) * 256 + threadIdx.x;
    long stride = (long)nCvtBlk * 256;
    for (; g < nGroups; g += stride) {
      const float* s; unsigned short* d; long j;
      if (g < GX) { s = x; d = xb; j = g; }
      else if (g < GX + GW) { s = w1; d = w1b; j = g - GX; }
      else { s = w2; d = w2b; j = g - GX - GW; }
      long e8 = j * 8;
      float4 v0 = *(const float4*)(s + e8);
      float4 v1 = *(const float4*)(s + e8 + 4);
      short8 pk;
      pk[0] = (short)f2bf(v0.x); pk[1] = (short)f2bf(v0.y);
      pk[2] = (short)f2bf(v0.z); pk[3] = (short)f2bf(v0.w);
      pk[4] = (short)f2bf(v1.x); pk[5] = (short)f2bf(v1.y);
      pk[6] = (short)f2bf(v1.z); pk[7] = (short)f2bf(v1.w);
      *(short8*)(d + e8) = pk;
    }
  }
}

// single block: register histogram -> wave reduce -> LDS combine -> poff prefix
__global__ __launch_bounds__(1024) void count_k(const int* __restrict__ eids,
                                                int* __restrict__ poff) {
  __shared__ int hist[16][EN];
  int tid = threadIdx.x, lane = tid & 63, w = tid >> 6;
  int c[EN];
#pragma unroll
  for (int e = 0; e < EN; ++e) c[e] = 0;
  for (int i = tid; i < 2 * TN; i += 1024) {
    int e = eids[i];
#pragma unroll
    for (int j = 0; j < EN; ++j) c[j] += (e == j) ? 1 : 0;
  }
#pragma unroll
  for (int j = 0; j < EN; ++j) {
#pragma unroll
    for (int off = 32; off > 0; off >>= 1) c[j] += __shfl_xor(c[j], off);
  }
  if (lane == 0) {
#pragma unroll
    for (int j = 0; j < EN; ++j) hist[w][j] = c[j];
  }
  __syncthreads();
  if (tid == 0) {
    int o = 0;
    for (int e = 0; e < EN; ++e) {
      int s = 0;
      for (int ww = 0; ww < 16; ++ww) s += hist[ww][e];
      poff[e] = o;
      o += (s + 127) & ~127;
    }
    poff[EN] = o;
  }
}

__global__ __launch_bounds__(256) void scatter_k(const int* __restrict__ eids,
                                                 const float* __restrict__ wts,
                                                 const int* __restrict__ poff,
                                                 int* __restrict__ cursor,
                                                 int* __restrict__ pairTok,
                                                 float* __restrict__ pairW,
                                                 int* __restrict__ slotPos) {
  int t = blockIdx.x * 256 + threadIdx.x;
#pragma unroll
  for (int k = 0; k < 2; ++k) {
    int e = eids[2 * t + k];
    int p = atomicAdd(&cursor[e], 1);
    int pos = poff[e] + p;
    pairTok[pos] = t;
    pairW[pos] = wts[2 * t + k];
    slotPos[2 * t + k] = pos;
  }
}

// out[t] = w0 * yb[pos0] + w1 * yb[pos1]
__global__ __launch_bounds__(256) void combine_k(const unsigned short* __restrict__ yb,
                                                 const float* __restrict__ wts,
                                                 const int* __restrict__ slotPos,
                                                 float* __restrict__ out) {
  int t = blockIdx.x;
  int p0 = slotPos[2 * t], p1 = slotPos[2 * t + 1];
  float w0 = wts[2 * t], w1 = wts[2 * t + 1];
  int c = threadIdx.x * 4;
  ushort4v y0 = *(const ushort4v*)(yb + (long)p0 * DN + c);
  ushort4v y1 = *(const ushort4v*)(yb + (long)p1 * DN + c);
  float4 o;
  o.x = w0 * bf2f(y0.x) + w1 * bf2f(y1.x);
  o.y = w0 * bf2f(y0.y) + w1 * bf2f(y1.y);
  o.z = w0 * bf2f(y0.z) + w1 * bf2f(y1.z);
  o.w = w0 * bf2f(y0.w) + w1 * bf2f(y1.w);
  *(float4*)(out + (long)t * DN + c) = o;
}

// ---- 128x128 GEMM, BK=32, 4 waves (2x2), 32 KiB LDS dbuf ----
// R13: launch_bounds(256,3) (R12's (256,5) cut VGPR budget to 48 -> accumulator
// spill -> 3.4 GB scratch traffic/dispatch, 6x regression). 3 blocks/CU = 12
// waves/CU (1.5x the BK=64 variant) with ~160-VGPR budget -> no spill.

#define BAR() { asm volatile("" ::: "memory"); __builtin_amdgcn_s_barrier(); \
                asm volatile("" ::: "memory"); }
#define LGKM0() { asm volatile("s_waitcnt lgkmcnt(0)" ::: "memory"); }

#define LDA4(PAR) { const char* _b = smem + (PAR)*8192;                              \
  _Pragma("unroll") for (int m = 0; m < 4; ++m) {                                    \
    int row = waveM*64 + m*16 + (lane & 15);                                         \
    a[m] = *(const short8*)(_b + row*64 + (((lane>>4) ^ ((row>>1)&3)) * 16)); } }

#define LDB4(PAR) { const char* _b = smem + 16384 + (PAR)*8192;                      \
  _Pragma("unroll") for (int n = 0; n < 4; ++n) {                                    \
    int row = waveN*64 + n*16 + (lane & 15);                                         \
    b[n] = *(const short8*)(_b + row*64 + (((lane>>4) ^ ((row>>1)&3)) * 16)); } }

#define MM16() { __builtin_amdgcn_s_setprio(1);                                      \
  _Pragma("unroll") for (int m = 0; m < 4; ++m)                                      \
    _Pragma("unroll") for (int n = 0; n < 4; ++n)                                    \
      acc[m][n] = __builtin_amdgcn_mfma_f32_16x16x32_bf16(a[m], b[n], acc[m][n], 0, 0, 0); \
  __builtin_amdgcn_s_setprio(0); }

template <int MODE, bool BBF16>
__global__ __launch_bounds__(256, 3) void moe_gemm128_k(
    const unsigned short* __restrict__ Ab, const void* __restrict__ Bsrc,
    void* __restrict__ OutP, const int* __restrict__ pairTok,
    const float* __restrict__ pairW, const int* __restrict__ poff, int chunkStart) {
  constexpr int KD = (MODE == 1) ? DN : HN;
  constexpr int ND = (MODE == 1) ? HN : DN;
  constexpr int SPLIT = (MODE == 3) ? 2 : 1;
  constexpr int KLEN = KD / SPLIT;
  constexpr int NT = KLEN / 32;

  extern __shared__ char smem[];

  int NX = gridDim.x;
  int NXY = NX * gridDim.y;
  int orig = blockIdx.y * NX + blockIdx.x;
  int qq = NXY >> 3, rrm = NXY & 7;
  int xcd = orig & 7, pos = orig >> 3;
  int wg = (xcd < rrm ? xcd * (qq + 1) : rrm * (qq + 1) + (xcd - rrm) * qq) + pos;

  int NYt = NXY / NX;
  const int GH = 8;
  int npg = GH * NX;
  int gid = wg / npg;
  int rem = wg - gid * npg;
  int rowsLeft = NYt - gid * GH;
  int gh = rowsLeft < GH ? rowsLeft : GH;
  int row = gid * GH + rem % gh;
  int col = rem / gh;
  int tileN = col * 128;
  int tileStart = chunkStart + row * 128;

  int Ppad = poff[EN];
  if (tileStart >= Ppad) return;
  int e = 0;
  while (e < EN - 1 && tileStart >= poff[e + 1]) ++e;

  int tid = threadIdx.x;
  int wid = tid >> 6, lane = tid & 63;
  int waveM = wid >> 1, waveN = wid & 1;
  int kbase = (MODE == 3) ? blockIdx.z * KLEN : 0;

  // staging: thread covers groups q=tid (row tid>>2) and q=256+tid (row 64+tid>>2)
  // linear slot q&3; global slot s = (q&3) ^ ((row>>1)&3); s same for both rows.
  int r0 = tid >> 2;
  int s0 = (tid & 3) ^ ((tid >> 3) & 3);
  const char* aSrc[2];
  const char* bSrc[2];
#pragma unroll
  for (int j = 0; j < 2; ++j) {
    int rw_ = j * 64 + r0;
    long abase;
    if (MODE == 1) {
      int tok = pairTok[tileStart + rw_];
      if (tok < 0) tok = 0;  // padding row: load token 0, result never read
      abase = (long)tok * KD;
    } else {
      abase = (long)(tileStart - chunkStart + rw_) * KD;
    }
    aSrc[j] = (const char*)(Ab + abase + kbase + s0 * 8);
    long bb = (long)e * ND * KD + (long)(tileN + rw_) * KD + kbase + s0 * 8;
    bSrc[j] = (const char*)Bsrc + bb * (BBF16 ? 2 : 4);
  }

  auto stageA = [&](int k0, int par) {
#pragma unroll
    for (int j = 0; j < 2; ++j)
      gload_lds16(aSrc[j] + (long)k0 * 2, smem + par * 8192 + (j * 256 + tid) * 16);
  };
  auto stageB = [&](int k0, int par) {
    if constexpr (BBF16) {
#pragma unroll
      for (int j = 0; j < 2; ++j)
        gload_lds16(bSrc[j] + (long)k0 * 2, smem + 16384 + par * 8192 + (j * 256 + tid) * 16);
    } else {
#pragma unroll
      for (int j = 0; j < 2; ++j) {
        const float4* pf = (const float4*)(bSrc[j] + (long)k0 * 4);
        float4 v0 = pf[0], v1 = pf[1];
        short8 pk;
        pk[0] = (short)f2bf(v0.x); pk[1] = (short)f2bf(v0.y);
        pk[2] = (short)f2bf(v0.z); pk[3] = (short)f2bf(v0.w);
        pk[4] = (short)f2bf(v1.x); pk[5] = (short)f2bf(v1.y);
        pk[6] = (short)f2bf(v1.z); pk[7] = (short)f2bf(v1.w);
        *(short8*)(smem + 16384 + par * 8192 + (j * 256 + tid) * 16) = pk;
      }
    }
  };

  f32x4 acc[4][4];
#pragma unroll
  for (int m = 0; m < 4; ++m)
#pragma unroll
    for (int n = 0; n < 4; ++n) acc[m][n] = (f32x4){0.f, 0.f, 0.f, 0.f};
  short8 a[4], b[4];

  // prologue: tile0 -> buf0, tile1 -> buf1 (8 loads); keep tile1's 4 in flight
  stageA(0, 0); stageB(0, 0);
  stageA(32, 1); stageB(32, 1);
  if constexpr (BBF16) {
    asm volatile("s_waitcnt vmcnt(4)" ::: "memory");
  } else {
    asm volatile("s_waitcnt vmcnt(0) lgkmcnt(0)" ::: "memory");
  }
  BAR();

  for (int t = 0; t < NT; ++t) {
    int P = t & 1;
    int k2 = (t + 2) * 32;
    LDA4(P); LDB4(P);
    LGKM0();        // own reads retired (data in regs)
    BAR();          // all waves' reads retired -> buf P is dead
    if (t + 2 < NT) { stageA(k2, P); stageB(k2, P); }  // refill dead buf
    MM16();
    if (BBF16 && t + 2 < NT) {
      asm volatile("s_waitcnt vmcnt(4)" ::: "memory");  // stage(t+1) landed
    } else {
      asm volatile("s_waitcnt vmcnt(0)" ::: "memory");
    }
    BAR();
  }

  if (MODE == 1) {
    unsigned short* hbp = (unsigned short*)OutP;
    int rl0 = tileStart - chunkStart + waveM * 64;
#pragma unroll
    for (int m = 0; m < 4; ++m) {
#pragma unroll
      for (int r = 0; r < 4; ++r) {
        int rl = rl0 + m * 16 + (lane >> 4) * 4 + r;
#pragma unroll
        for (int n = 0; n < 4; ++n) {
          int coln = tileN + waveN * 64 + n * 16 + (lane & 15);
          hbp[(long)rl * HN + coln] = f2bf(gelu_f(acc[m][n][r]));
        }
      }
    }
  } else if (MODE == 2) {
    unsigned short* ybp = (unsigned short*)OutP;
#pragma unroll
    for (int m = 0; m < 4; ++m) {
#pragma unroll
      for (int r = 0; r < 4; ++r) {
        int p = tileStart + waveM * 64 + m * 16 + (lane >> 4) * 4 + r;
#pragma unroll
        for (int n = 0; n < 4; ++n) {
          int coln = tileN + waveN * 64 + n * 16 + (lane & 15);
          ybp[(long)p * ND + coln] = f2bf(acc[m][n][r]);
        }
      }
    }
  } else {
    float* outF = (float*)OutP;
#pragma unroll
    for (int m = 0; m < 4; ++m) {
#pragma unroll
      for (int r = 0; r < 4; ++r) {
        int p = tileStart + waveM * 64 + m * 16 + (lane >> 4) * 4 + r;
        int tok = pairTok[p];
        if (tok < 0) continue;
        float wv = pairW[p];
#pragma unroll
        for (int n = 0; n < 4; ++n) {
          int coln = tileN + waveN * 64 + n * 16 + (lane & 15);
          atomicAdd(&outF[(long)tok * DN + coln], wv * acc[m][n][r]);
        }
      }
    }
  }
}

extern "C" void kernel_launch(void* const* d_in, const int* in_sizes, int n_in,
                              void* d_out, int out_size, void* d_ws, size_t ws_size,
                              hipStream_t stream) {
  const float* x = (const float*)d_in[0];
  const float* rw = (const float*)d_in[1];
  const float* w1 = (const float*)d_in[2];
  const float* w2 = (const float*)d_in[3];
  char* W = (char*)d_ws;
  size_t off = 0;
  auto alloc = [&](size_t sz) {
    off = (off + 255) & ~(size_t)255;
    size_t r = off; off += sz; return r;
  };
  size_t ctrlO = alloc(256);  // cursor[8], poff[9]
  size_t eidsO = alloc((size_t)TN * 2 * 4);
  size_t wtsO  = alloc((size_t)TN * 2 * 4);
  size_t ptokO = alloc((size_t)PADMAX * 4);
  size_t pwO   = alloc((size_t)PADMAX * 4);
  size_t sposO = alloc((size_t)TN * 2 * 4);
  size_t xbO   = alloc((size_t)TN * DN * 2);
  size_t wB = (size_t)EN * HN * DN * 2;
  size_t afterFixed = (off + 255) & ~(size_t)255;
  bool bw = ws_size >= afterFixed + 2 * wB + (size_t)128 * HN * 2 + 4096;
  size_t w1bO = 0, w2bO = 0;
  if (bw) { w1bO = alloc(wB); w2bO = alloc(wB); }
  size_t ybB = (size_t)PADMAX * DN * 2;
  size_t afterW = (off + 255) & ~(size_t)255;
  bool dense = ws_size >= afterW + ybB + (size_t)128 * HN * 2 + 4096;
  size_t ybO = 0;
  if (dense) ybO = alloc(ybB);
  size_t hbase = (off + 255) & ~(size_t)255;
  size_t avail = ws_size > hbase ? ws_size - hbase : (size_t)128 * HN * 2;
  long Cl = (long)(avail / ((size_t)HN * 2));
  if (Cl > PADMAX) Cl = PADMAX;
  Cl &= ~127l;
  if (Cl < 128) Cl = 128;
  int C = (int)Cl;
  size_t hbO = alloc((size_t)C * HN * 2);
  int nCh = (PADMAX + C - 1) / C;

  int* cursor = (int*)(W + ctrlO);
  int* poff = cursor + 8;
  int* eids = (int*)(W + eidsO);
  float* wts = (float*)(W + wtsO);
  int* pairTok = (int*)(W + ptokO);
  float* pairW = (float*)(W + pwO);
  int* slotPos = (int*)(W + sposO);
  unsigned short* xb = (unsigned short*)(W + xbO);
  unsigned short* hb = (unsigned short*)(W + hbO);
  unsigned short* yb = (unsigned short*)(W + ybO);

  hipFuncSetAttribute(reinterpret_cast<const void*>(moe_gemm128_k<1, true>),
                      hipFuncAttributeMaxDynamicSharedMemorySize, 32768);
  hipFuncSetAttribute(reinterpret_cast<const void*>(moe_gemm128_k<2, true>),
                      hipFuncAttributeMaxDynamicSharedMemorySize, 32768);
  hipFuncSetAttribute(reinterpret_cast<const void*>(moe_gemm128_k<3, true>),
                      hipFuncAttributeMaxDynamicSharedMemorySize, 32768);
  hipFuncSetAttribute(reinterpret_cast<const void*>(moe_gemm128_k<1, false>),
                      hipFuncAttributeMaxDynamicSharedMemorySize, 32768);
  hipFuncSetAttribute(reinterpret_cast<const void*>(moe_gemm128_k<2, false>),
                      hipFuncAttributeMaxDynamicSharedMemorySize, 32768);
  hipFuncSetAttribute(reinterpret_cast<const void*>(moe_gemm128_k<3, false>),
                      hipFuncAttributeMaxDynamicSharedMemorySize, 32768);

  hipMemsetAsync(W + ctrlO, 0, 256, stream);
  hipMemsetAsync(W + ptokO, 0xFF, (size_t)PADMAX * 4, stream);  // pairTok = -1
  if (!dense) hipMemsetAsync(d_out, 0, (size_t)TN * DN * 4, stream);

  const int nCvtBlk = 4096;
  const long GX = (long)TN * DN / 8;
  const long GW = (long)EN * HN * DN / 8;
  long nGroups = GX + (bw ? 2 * GW : 0);
  prep_k<<<TN / 4 + nCvtBlk, 256, 0, stream>>>(
      x, rw, w1, w2, xb,
      bw ? (unsigned short*)(W + w1bO) : nullptr,
      bw ? (unsigned short*)(W + w2bO) : nullptr,
      eids, wts, nCvtBlk, nGroups);
  count_k<<<1, 1024, 0, stream>>>(eids, poff);
  scatter_k<<<TN / 256, 256, 0, stream>>>(eids, wts, poff, cursor, pairTok, pairW, slotPos);

  int Ctiles = C / 128;
  for (int c = 0; c < nCh; ++c) {
    int cs = c * C;
    if (bw) {
      moe_gemm128_k<1, true><<<dim3(HN / 128, Ctiles, 1), 256, 32768, stream>>>(
          xb, W + w1bO, hb, pairTok, pairW, poff, cs);
      if (dense) {
        moe_gemm128_k<2, true><<<dim3(DN / 128, Ctiles, 1), 256, 32768, stream>>>(
            hb, W + w2bO, yb, pairTok, pairW, poff, cs);
      } else {
        moe_gemm128_k<3, true><<<dim3(DN / 128, Ctiles, 2), 256, 32768, stream>>>(
            hb, W + w2bO, d_out, pairTok, pairW, poff, cs);
      }
    } else {
      moe_gemm128_k<1, false><<<dim3(HN / 128, Ctiles, 1), 256, 32768, stream>>>(
          xb, w1, hb, pairTok, pairW, poff, cs);
      if (dense) {
        moe_gemm128_k<2, false><<<dim3(DN / 128, Ctiles, 1), 256, 32768, stream>>>(
            hb, w2, yb, pairTok, pairW, poff, cs);
      } else {
        moe_gemm128_k<3, false><<<dim3(DN / 128, Ctiles, 2), 256, 32768, stream>>>(
            hb, w2, d_out, pairTok, pairW, poff, cs);
      }
    }
  }
  if (dense) {
    combine_k<<<TN, 256, 0, stream>>>(yb, wts, slotPos, (float*)d_out);
  }
}

// Round 14
// 542.408 us; speedup vs baseline: 4.6904x; 1.0980x over previous
//
#include <hip/hip_runtime.h>
#include <hip/hip_bf16.h>
#include <cstdint>

#define TN 8192
#define DN 1024
#define HN 4096
#define EN 8
#define PADMAX 18432  // >= 16384 + 8*127 worst-case pad(128), rounded up

typedef __attribute__((ext_vector_type(8))) short short8;
typedef __attribute__((ext_vector_type(4))) float f32x4;
typedef __attribute__((ext_vector_type(4))) unsigned short ushort4v;

__device__ inline unsigned short f2bf(float f) {
  unsigned u = __builtin_bit_cast(unsigned, f);
  u = u + 0x7fffu + ((u >> 16) & 1u);
  return (unsigned short)(u >> 16);
}
__device__ inline float bf2f(unsigned short u) {
  unsigned v = ((unsigned)u) << 16;
  return __builtin_bit_cast(float, v);
}

// exact tanh-GELU identity: 0.5*v*(1+tanh(z)) == v * sigmoid(2z)
__device__ inline float gelu_f(float v) {
  float z2 = 1.5957691216057308f * (v + 0.044715f * v * v * v);
  return v / (1.f + __expf(-z2));
}

__device__ inline void gload_lds16(const void* g, void* l) {
  __builtin_amdgcn_global_load_lds(
      (const __attribute__((address_space(1))) unsigned int*)g,
      (__attribute__((address_space(3))) unsigned int*)l, 16, 0, 0);
}

// prep: blocks [0,2048) = atomic-free router; rest = grid-stride bf16 cvt
// of x and w1 ONLY (w2 cvt rides inside fc1's z=1 blocks, overlapped).
__global__ __launch_bounds__(256) void prep_k(const float* __restrict__ x,
                                              const float* __restrict__ rw,
                                              const float* __restrict__ w1,
                                              unsigned short* __restrict__ xb,
                                              unsigned short* __restrict__ w1b,
                                              int* __restrict__ eids,
                                              float* __restrict__ wts,
                                              int nCvtBlk, long nGroups) {
  if (blockIdx.x < TN / 4) {
    int wid = threadIdx.x >> 6, lane = threadIdx.x & 63;
    int t = blockIdx.x * 4 + wid;
    const float* xr = x + (long)t * DN;
    float a[EN];
#pragma unroll
    for (int e = 0; e < EN; ++e) a[e] = 0.f;
    for (int k = lane; k < DN; k += 64) {
      float xv = xr[k];
#pragma unroll
      for (int e = 0; e < EN; ++e) a[e] += xv * rw[e * DN + k];
    }
#pragma unroll
    for (int off = 32; off > 0; off >>= 1) {
#pragma unroll
      for (int e = 0; e < EN; ++e) a[e] += __shfl_xor(a[e], off);
    }
    if (lane == 0) {
      float mx = a[0];
#pragma unroll
      for (int e = 1; e < EN; ++e) mx = fmaxf(mx, a[e]);
      float p[EN], s = 0.f;
#pragma unroll
      for (int e = 0; e < EN; ++e) { p[e] = __expf(a[e] - mx); s += p[e]; }
      int e0 = 0; float b0 = p[0];
#pragma unroll
      for (int e = 1; e < EN; ++e) if (p[e] > b0) { b0 = p[e]; e0 = e; }
      int e1 = -1; float b1 = -1.f;
#pragma unroll
      for (int e = 0; e < EN; ++e) if (e != e0 && p[e] > b1) { b1 = p[e]; e1 = e; }
      float inv = 1.f / s;
      eids[2 * t] = e0; eids[2 * t + 1] = e1;
      wts[2 * t] = b0 * inv; wts[2 * t + 1] = b1 * inv;
    }
  } else {
    const long GX = (long)TN * DN / 8;
    long g = (long)(blockIdx.x - TN / 4) * 256 + threadIdx.x;
    long stride = (long)nCvtBlk * 256;
    for (; g < nGroups; g += stride) {
      const float* s; unsigned short* d; long j;
      if (g < GX) { s = x; d = xb; j = g; }
      else { s = w1; d = w1b; j = g - GX; }
      long e8 = j * 8;
      float4 v0 = *(const float4*)(s + e8);
      float4 v1 = *(const float4*)(s + e8 + 4);
      short8 pk;
      pk[0] = (short)f2bf(v0.x); pk[1] = (short)f2bf(v0.y);
      pk[2] = (short)f2bf(v0.z); pk[3] = (short)f2bf(v0.w);
      pk[4] = (short)f2bf(v1.x); pk[5] = (short)f2bf(v1.y);
      pk[6] = (short)f2bf(v1.z); pk[7] = (short)f2bf(v1.w);
      *(short8*)(d + e8) = pk;
    }
  }
}

// single block: register histogram -> wave reduce -> LDS combine -> poff prefix
__global__ __launch_bounds__(1024) void count_k(const int* __restrict__ eids,
                                                int* __restrict__ poff) {
  __shared__ int hist[16][EN];
  int tid = threadIdx.x, lane = tid & 63, w = tid >> 6;
  int c[EN];
#pragma unroll
  for (int e = 0; e < EN; ++e) c[e] = 0;
  for (int i = tid; i < 2 * TN; i += 1024) {
    int e = eids[i];
#pragma unroll
    for (int j = 0; j < EN; ++j) c[j] += (e == j) ? 1 : 0;
  }
#pragma unroll
  for (int j = 0; j < EN; ++j) {
#pragma unroll
    for (int off = 32; off > 0; off >>= 1) c[j] += __shfl_xor(c[j], off);
  }
  if (lane == 0) {
#pragma unroll
    for (int j = 0; j < EN; ++j) hist[w][j] = c[j];
  }
  __syncthreads();
  if (tid == 0) {
    int o = 0;
    for (int e = 0; e < EN; ++e) {
      int s = 0;
      for (int ww = 0; ww < 16; ++ww) s += hist[ww][e];
      poff[e] = o;
      o += (s + 127) & ~127;
    }
    poff[EN] = o;
  }
}

__global__ __launch_bounds__(256) void scatter_k(const int* __restrict__ eids,
                                                 const float* __restrict__ wts,
                                                 const int* __restrict__ poff,
                                                 int* __restrict__ cursor,
                                                 int* __restrict__ pairTok,
                                                 float* __restrict__ pairW,
                                                 int* __restrict__ slotPos) {
  int t = blockIdx.x * 256 + threadIdx.x;
#pragma unroll
  for (int k = 0; k < 2; ++k) {
    int e = eids[2 * t + k];
    int p = atomicAdd(&cursor[e], 1);
    int pos = poff[e] + p;
    pairTok[pos] = t;
    pairW[pos] = wts[2 * t + k];
    slotPos[2 * t + k] = pos;
  }
}

// out[t] = w0 * yb[pos0] + w1 * yb[pos1]
__global__ __launch_bounds__(256) void combine_k(const unsigned short* __restrict__ yb,
                                                 const float* __restrict__ wts,
                                                 const int* __restrict__ slotPos,
                                                 float* __restrict__ out) {
  int t = blockIdx.x;
  int p0 = slotPos[2 * t], p1 = slotPos[2 * t + 1];
  float w0 = wts[2 * t], w1 = wts[2 * t + 1];
  int c = threadIdx.x * 4;
  ushort4v y0 = *(const ushort4v*)(yb + (long)p0 * DN + c);
  ushort4v y1 = *(const ushort4v*)(yb + (long)p1 * DN + c);
  float4 o;
  o.x = w0 * bf2f(y0.x) + w1 * bf2f(y1.x);
  o.y = w0 * bf2f(y0.y) + w1 * bf2f(y1.y);
  o.z = w0 * bf2f(y0.z) + w1 * bf2f(y1.z);
  o.w = w0 * bf2f(y0.w) + w1 * bf2f(y1.w);
  *(float4*)(out + (long)t * DN + c) = o;
}

// ---- 128x128 GEMM, BK=64, 4 waves (2x2), 64 KiB LDS dbuf -> 2 blocks/CU ----
// R14: GEMM core reverted to R11 (confirmed best across 3 schedules, 2 tiles,
// 2 occupancy points). MODE 1 gains z=1 "helper" blocks that convert w2
// fp32->bf16 concurrently (fc1 uses only ~1.5/6.3 TB/s; w2b needed only by
// the later fc2 launch). GH=8 group tiling, XCD swizzle, counted vmcnt(8).

#define BAR() { asm volatile("" ::: "memory"); __builtin_amdgcn_s_barrier(); \
                asm volatile("" ::: "memory"); }
#define LGKM0() { asm volatile("s_waitcnt lgkmcnt(0)" ::: "memory"); }

#define LDA4(PAR) { const char* _b = smem + (PAR)*16384;                             \
  _Pragma("unroll") for (int m = 0; m < 4; ++m) {                                    \
    int row = waveM*64 + m*16 + (lane & 15); int cb = row * 128;                     \
    a[m][0] = *(const short8*)(_b + cb + (((lane>>4) ^ (row&7)) * 16));              \
    a[m][1] = *(const short8*)(_b + cb + (((4 + (lane>>4)) ^ (row&7)) * 16)); } }

#define LDB2(NH, PAR) { const char* _b = smem + 32768 + (PAR)*16384;                 \
  _Pragma("unroll") for (int n = 0; n < 2; ++n) {                                    \
    int row = waveN*64 + ((NH)*2+n)*16 + (lane & 15); int cb = row * 128;            \
    b[(NH)*2+n][0] = *(const short8*)(_b + cb + (((lane>>4) ^ (row&7)) * 16));       \
    b[(NH)*2+n][1] = *(const short8*)(_b + cb + (((4 + (lane>>4)) ^ (row&7)) * 16)); } }

#define MM16(NH) { __builtin_amdgcn_s_setprio(1);                                    \
  _Pragma("unroll") for (int m = 0; m < 4; ++m)                                      \
    _Pragma("unroll") for (int n = 0; n < 2; ++n) {                                  \
      acc[m][(NH)*2+n] = __builtin_amdgcn_mfma_f32_16x16x32_bf16(                    \
          a[m][0], b[(NH)*2+n][0], acc[m][(NH)*2+n], 0, 0, 0);                       \
      acc[m][(NH)*2+n] = __builtin_amdgcn_mfma_f32_16x16x32_bf16(                    \
          a[m][1], b[(NH)*2+n][1], acc[m][(NH)*2+n], 0, 0, 0); }                     \
  __builtin_amdgcn_s_setprio(0); }

template <int MODE, bool BBF16>
__global__ __launch_bounds__(256, 2) void moe_gemm128_k(
    const unsigned short* __restrict__ Ab, const void* __restrict__ Bsrc,
    void* __restrict__ OutP, const int* __restrict__ pairTok,
    const float* __restrict__ pairW, const int* __restrict__ poff, int chunkStart,
    const float* __restrict__ w2src, unsigned short* __restrict__ w2dst) {
  constexpr int KD = (MODE == 1) ? DN : HN;
  constexpr int ND = (MODE == 1) ? HN : DN;
  constexpr int SPLIT = (MODE == 3) ? 2 : 1;
  constexpr int KLEN = KD / SPLIT;
  constexpr int NT = KLEN / 64;

  extern __shared__ char smem[];

  if (MODE == 1 && blockIdx.z == 1) {
    // helper blocks: grid-stride w2 fp32->bf16 cvt, overlapped with fc1 GEMM
    const long nG = (long)EN * HN * DN / 8;
    long b = (long)blockIdx.y * gridDim.x + blockIdx.x;
    long g = b * 256 + threadIdx.x;
    long stride = (long)gridDim.x * gridDim.y * 256;
    for (; g < nG; g += stride) {
      long e8 = g * 8;
      float4 v0 = *(const float4*)(w2src + e8);
      float4 v1 = *(const float4*)(w2src + e8 + 4);
      short8 pk;
      pk[0] = (short)f2bf(v0.x); pk[1] = (short)f2bf(v0.y);
      pk[2] = (short)f2bf(v0.z); pk[3] = (short)f2bf(v0.w);
      pk[4] = (short)f2bf(v1.x); pk[5] = (short)f2bf(v1.y);
      pk[6] = (short)f2bf(v1.z); pk[7] = (short)f2bf(v1.w);
      *(short8*)(w2dst + e8) = pk;
    }
    return;
  }

  int NX = gridDim.x;
  int NXY = NX * gridDim.y;
  int orig = blockIdx.y * NX + blockIdx.x;
  int qq = NXY >> 3, rrm = NXY & 7;
  int xcd = orig & 7, pos = orig >> 3;
  int wg = (xcd < rrm ? xcd * (qq + 1) : rrm * (qq + 1) + (xcd - rrm) * qq) + pos;

  int NYt = NXY / NX;
  const int GH = 8;
  int npg = GH * NX;
  int gid = wg / npg;
  int rem = wg - gid * npg;
  int rowsLeft = NYt - gid * GH;
  int gh = rowsLeft < GH ? rowsLeft : GH;
  int row = gid * GH + rem % gh;
  int col = rem / gh;
  int tileN = col * 128;
  int tileStart = chunkStart + row * 128;

  int Ppad = poff[EN];
  if (tileStart >= Ppad) return;
  int e = 0;
  while (e < EN - 1 && tileStart >= poff[e + 1]) ++e;

  int tid = threadIdx.x;
  int wid = tid >> 6, lane = tid & 63;
  int waveM = wid >> 1, waveN = wid & 1;
  int kbase = (MODE == 3) ? blockIdx.z * KLEN : 0;

  int r0 = tid >> 3;
  const char* aSrc[4];
  const char* bSrc[4];
#pragma unroll
  for (int j = 0; j < 4; ++j) {
    int rw_ = j * 32 + r0;
    int s = (tid & 7) ^ (rw_ & 7);
    long abase;
    if (MODE == 1) {
      int tok = pairTok[tileStart + rw_];
      if (tok < 0) tok = 0;  // padding row: load token 0, result never read
      abase = (long)tok * KD;
    } else {
      abase = (long)(tileStart - chunkStart + rw_) * KD;
    }
    aSrc[j] = (const char*)(Ab + abase + kbase + s * 8);
    long bb = (long)e * ND * KD + (long)(tileN + rw_) * KD + kbase + s * 8;
    bSrc[j] = (const char*)Bsrc + bb * (BBF16 ? 2 : 4);
  }

  auto stageA = [&](int k0, int par) {
#pragma unroll
    for (int j = 0; j < 4; ++j)
      gload_lds16(aSrc[j] + (long)k0 * 2, smem + par * 16384 + (j * 256 + tid) * 16);
  };
  auto stageB = [&](int k0, int par) {
    if constexpr (BBF16) {
#pragma unroll
      for (int j = 0; j < 4; ++j)
        gload_lds16(bSrc[j] + (long)k0 * 2, smem + 32768 + par * 16384 + (j * 256 + tid) * 16);
    } else {
#pragma unroll
      for (int j = 0; j < 4; ++j) {
        const float4* pf = (const float4*)(bSrc[j] + (long)k0 * 4);
        float4 v0 = pf[0], v1 = pf[1];
        short8 pk;
        pk[0] = (short)f2bf(v0.x); pk[1] = (short)f2bf(v0.y);
        pk[2] = (short)f2bf(v0.z); pk[3] = (short)f2bf(v0.w);
        pk[4] = (short)f2bf(v1.x); pk[5] = (short)f2bf(v1.y);
        pk[6] = (short)f2bf(v1.z); pk[7] = (short)f2bf(v1.w);
        *(short8*)(smem + 32768 + par * 16384 + (j * 256 + tid) * 16) = pk;
      }
    }
  };

  f32x4 acc[4][4];
#pragma unroll
  for (int m = 0; m < 4; ++m)
#pragma unroll
    for (int n = 0; n < 4; ++n) acc[m][n] = (f32x4){0.f, 0.f, 0.f, 0.f};
  short8 a[4][2], b[4][2];

  stageA(0, 0); stageB(0, 0);
  stageA(64, 1); stageB(64, 1);
  if constexpr (BBF16) {
    asm volatile("s_waitcnt vmcnt(8)" ::: "memory");
  } else {
    asm volatile("s_waitcnt vmcnt(0) lgkmcnt(0)" ::: "memory");
  }
  BAR();

  for (int t = 0; t < NT; ++t) {
    int P = t & 1;
    int k2 = (t + 2) * 64;
    LDA4(P); LDB2(0, P);
    BAR(); LGKM0();
    MM16(0);
    BAR();
    LDB2(1, P);
    if (t + 2 < NT) stageA(k2, P);
    BAR(); LGKM0();
    MM16(1);
    if (t + 2 < NT) stageB(k2, P);
    if (BBF16 && t + 2 < NT) {
      asm volatile("s_waitcnt vmcnt(8)" ::: "memory");
    } else {
      asm volatile("s_waitcnt vmcnt(0)" ::: "memory");
    }
    BAR();
  }

  if (MODE == 1) {
    unsigned short* hbp = (unsigned short*)OutP;
    int rl0 = tileStart - chunkStart + waveM * 64;
#pragma unroll
    for (int m = 0; m < 4; ++m) {
#pragma unroll
      for (int r = 0; r < 4; ++r) {
        int rl = rl0 + m * 16 + (lane >> 4) * 4 + r;
#pragma unroll
        for (int n = 0; n < 4; ++n) {
          int coln = tileN + waveN * 64 + n * 16 + (lane & 15);
          hbp[(long)rl * HN + coln] = f2bf(gelu_f(acc[m][n][r]));
        }
      }
    }
  } else if (MODE == 2) {
    unsigned short* ybp = (unsigned short*)OutP;
#pragma unroll
    for (int m = 0; m < 4; ++m) {
#pragma unroll
      for (int r = 0; r < 4; ++r) {
        int p = tileStart + waveM * 64 + m * 16 + (lane >> 4) * 4 + r;
#pragma unroll
        for (int n = 0; n < 4; ++n) {
          int coln = tileN + waveN * 64 + n * 16 + (lane & 15);
          ybp[(long)p * ND + coln] = f2bf(acc[m][n][r]);
        }
      }
    }
  } else {
    float* outF = (float*)OutP;
#pragma unroll
    for (int m = 0; m < 4; ++m) {
#pragma unroll
      for (int r = 0; r < 4; ++r) {
        int p = tileStart + waveM * 64 + m * 16 + (lane >> 4) * 4 + r;
        int tok = pairTok[p];
        if (tok < 0) continue;
        float wv = pairW[p];
#pragma unroll
        for (int n = 0; n < 4; ++n) {
          int coln = tileN + waveN * 64 + n * 16 + (lane & 15);
          atomicAdd(&outF[(long)tok * DN + coln], wv * acc[m][n][r]);
        }
      }
    }
  }
}

extern "C" void kernel_launch(void* const* d_in, const int* in_sizes, int n_in,
                              void* d_out, int out_size, void* d_ws, size_t ws_size,
                              hipStream_t stream) {
  const float* x = (const float*)d_in[0];
  const float* rw = (const float*)d_in[1];
  const float* w1 = (const float*)d_in[2];
  const float* w2 = (const float*)d_in[3];
  char* W = (char*)d_ws;
  size_t off = 0;
  auto alloc = [&](size_t sz) {
    off = (off + 255) & ~(size_t)255;
    size_t r = off; off += sz; return r;
  };
  size_t ctrlO = alloc(256);  // cursor[8], poff[9]
  size_t eidsO = alloc((size_t)TN * 2 * 4);
  size_t wtsO  = alloc((size_t)TN * 2 * 4);
  size_t ptokO = alloc((size_t)PADMAX * 4);
  size_t pwO   = alloc((size_t)PADMAX * 4);
  size_t sposO = alloc((size_t)TN * 2 * 4);
  size_t xbO   = alloc((size_t)TN * DN * 2);
  size_t wB = (size_t)EN * HN * DN * 2;
  size_t afterFixed = (off + 255) & ~(size_t)255;
  bool bw = ws_size >= afterFixed + 2 * wB + (size_t)128 * HN * 2 + 4096;
  size_t w1bO = 0, w2bO = 0;
  if (bw) { w1bO = alloc(wB); w2bO = alloc(wB); }
  size_t ybB = (size_t)PADMAX * DN * 2;
  size_t afterW = (off + 255) & ~(size_t)255;
  bool dense = ws_size >= afterW + ybB + (size_t)128 * HN * 2 + 4096;
  size_t ybO = 0;
  if (dense) ybO = alloc(ybB);
  size_t hbase = (off + 255) & ~(size_t)255;
  size_t avail = ws_size > hbase ? ws_size - hbase : (size_t)128 * HN * 2;
  long Cl = (long)(avail / ((size_t)HN * 2));
  if (Cl > PADMAX) Cl = PADMAX;
  Cl &= ~127l;
  if (Cl < 128) Cl = 128;
  int C = (int)Cl;
  size_t hbO = alloc((size_t)C * HN * 2);
  int nCh = (PADMAX + C - 1) / C;

  int* cursor = (int*)(W + ctrlO);
  int* poff = cursor + 8;
  int* eids = (int*)(W + eidsO);
  float* wts = (float*)(W + wtsO);
  int* pairTok = (int*)(W + ptokO);
  float* pairW = (float*)(W + pwO);
  int* slotPos = (int*)(W + sposO);
  unsigned short* xb = (unsigned short*)(W + xbO);
  unsigned short* hb = (unsigned short*)(W + hbO);
  unsigned short* yb = (unsigned short*)(W + ybO);

  hipFuncSetAttribute(reinterpret_cast<const void*>(moe_gemm128_k<1, true>),
                      hipFuncAttributeMaxDynamicSharedMemorySize, 65536);
  hipFuncSetAttribute(reinterpret_cast<const void*>(moe_gemm128_k<2, true>),
                      hipFuncAttributeMaxDynamicSharedMemorySize, 65536);
  hipFuncSetAttribute(reinterpret_cast<const void*>(moe_gemm128_k<3, true>),
                      hipFuncAttributeMaxDynamicSharedMemorySize, 65536);
  hipFuncSetAttribute(reinterpret_cast<const void*>(moe_gemm128_k<1, false>),
                      hipFuncAttributeMaxDynamicSharedMemorySize, 65536);
  hipFuncSetAttribute(reinterpret_cast<const void*>(moe_gemm128_k<2, false>),
                      hipFuncAttributeMaxDynamicSharedMemorySize, 65536);
  hipFuncSetAttribute(reinterpret_cast<const void*>(moe_gemm128_k<3, false>),
                      hipFuncAttributeMaxDynamicSharedMemorySize, 65536);

  hipMemsetAsync(W + ctrlO, 0, 256, stream);
  hipMemsetAsync(W + ptokO, 0xFF, (size_t)PADMAX * 4, stream);  // pairTok = -1
  if (!dense) hipMemsetAsync(d_out, 0, (size_t)TN * DN * 4, stream);

  const int nCvtBlk = 4096;
  const long GX = (long)TN * DN / 8;
  const long GW = (long)EN * HN * DN / 8;
  long nGroups = GX + (bw ? GW : 0);  // x + w1 only
  prep_k<<<TN / 4 + nCvtBlk, 256, 0, stream>>>(
      x, rw, w1, xb,
      bw ? (unsigned short*)(W + w1bO) : nullptr,
      eids, wts, nCvtBlk, nGroups);
  count_k<<<1, 1024, 0, stream>>>(eids, poff);
  scatter_k<<<TN / 256, 256, 0, stream>>>(eids, wts, poff, cursor, pairTok, pairW, slotPos);

  int Ctiles = C / 128;
  for (int c = 0; c < nCh; ++c) {
    int cs = c * C;
    if (bw) {
      // z=0: fc1 GEMM; z=1 (first chunk only): w2 cvt overlapped
      moe_gemm128_k<1, true><<<dim3(HN / 128, Ctiles, c == 0 ? 2 : 1), 256, 65536, stream>>>(
          xb, W + w1bO, hb, pairTok, pairW, poff, cs, w2,
          (unsigned short*)(W + w2bO));
      if (dense) {
        moe_gemm128_k<2, true><<<dim3(DN / 128, Ctiles, 1), 256, 65536, stream>>>(
            hb, W + w2bO, yb, pairTok, pairW, poff, cs, nullptr, nullptr);
      } else {
        moe_gemm128_k<3, true><<<dim3(DN / 128, Ctiles, 2), 256, 65536, stream>>>(
            hb, W + w2bO, d_out, pairTok, pairW, poff, cs, nullptr, nullptr);
      }
    } else {
      moe_gemm128_k<1, false><<<dim3(HN / 128, Ctiles, 1), 256, 65536, stream>>>(
          xb, w1, hb, pairTok, pairW, poff, cs, nullptr, nullptr);
      if (dense) {
        moe_gemm128_k<2, false><<<dim3(DN / 128, Ctiles, 1), 256, 65536, stream>>>(
            hb, w2, yb, pairTok, pairW, poff, cs, nullptr, nullptr);
      } else {
        moe_gemm128_k<3, false><<<dim3(DN / 128, Ctiles, 2), 256, 65536, stream>>>(
            hb, w2, d_out, pairTok, pairW, poff, cs, nullptr, nullptr);
      }
    }
  }
  if (dense) {
    combine_k<<<TN, 256, 0, stream>>>(yb, wts, slotPos, (float*)d_out);
  }
}

// Round 15
// 538.154 us; speedup vs baseline: 4.7275x; 1.0079x over previous
//
#include <hip/hip_runtime.h>
#include <hip/hip_bf16.h>
#include <cstdint>

#define TN 8192
#define DN 1024
#define HN 4096
#define EN 8
#define PADMAX 18432  // >= 16384 + 8*127 worst-case pad(128), rounded up

typedef __attribute__((ext_vector_type(8))) short short8;
typedef __attribute__((ext_vector_type(4))) float f32x4;
typedef __attribute__((ext_vector_type(4))) unsigned short ushort4v;

__device__ inline unsigned short f2bf(float f) {
  unsigned u = __builtin_bit_cast(unsigned, f);
  u = u + 0x7fffu + ((u >> 16) & 1u);
  return (unsigned short)(u >> 16);
}
__device__ inline float bf2f(unsigned short u) {
  unsigned v = ((unsigned)u) << 16;
  return __builtin_bit_cast(float, v);
}

// exact tanh-GELU identity: 0.5*v*(1+tanh(z)) == v * sigmoid(2z)
__device__ inline float gelu_f(float v) {
  float z2 = 1.5957691216057308f * (v + 0.044715f * v * v * v);
  return v / (1.f + __expf(-z2));
}

__device__ inline void gload_lds16(const void* g, void* l) {
  __builtin_amdgcn_global_load_lds(
      (const __attribute__((address_space(1))) unsigned int*)g,
      (__attribute__((address_space(3))) unsigned int*)l, 16, 0, 0);
}

// prep: blocks [0,2048) = atomic-free router; rest = grid-stride bf16 cvt
// of x and w1 ONLY (w2 cvt rides inside fc1's z=1 blocks, overlapped).
__global__ __launch_bounds__(256) void prep_k(const float* __restrict__ x,
                                              const float* __restrict__ rw,
                                              const float* __restrict__ w1,
                                              unsigned short* __restrict__ xb,
                                              unsigned short* __restrict__ w1b,
                                              int* __restrict__ eids,
                                              float* __restrict__ wts,
                                              int nCvtBlk, long nGroups) {
  if (blockIdx.x < TN / 4) {
    int wid = threadIdx.x >> 6, lane = threadIdx.x & 63;
    int t = blockIdx.x * 4 + wid;
    const float* xr = x + (long)t * DN;
    float a[EN];
#pragma unroll
    for (int e = 0; e < EN; ++e) a[e] = 0.f;
    for (int k = lane; k < DN; k += 64) {
      float xv = xr[k];
#pragma unroll
      for (int e = 0; e < EN; ++e) a[e] += xv * rw[e * DN + k];
    }
#pragma unroll
    for (int off = 32; off > 0; off >>= 1) {
#pragma unroll
      for (int e = 0; e < EN; ++e) a[e] += __shfl_xor(a[e], off);
    }
    if (lane == 0) {
      float mx = a[0];
#pragma unroll
      for (int e = 1; e < EN; ++e) mx = fmaxf(mx, a[e]);
      float p[EN], s = 0.f;
#pragma unroll
      for (int e = 0; e < EN; ++e) { p[e] = __expf(a[e] - mx); s += p[e]; }
      int e0 = 0; float b0 = p[0];
#pragma unroll
      for (int e = 1; e < EN; ++e) if (p[e] > b0) { b0 = p[e]; e0 = e; }
      int e1 = -1; float b1 = -1.f;
#pragma unroll
      for (int e = 0; e < EN; ++e) if (e != e0 && p[e] > b1) { b1 = p[e]; e1 = e; }
      float inv = 1.f / s;
      eids[2 * t] = e0; eids[2 * t + 1] = e1;
      wts[2 * t] = b0 * inv; wts[2 * t + 1] = b1 * inv;
    }
  } else {
    const long GX = (long)TN * DN / 8;
    long g = (long)(blockIdx.x - TN / 4) * 256 + threadIdx.x;
    long stride = (long)nCvtBlk * 256;
    for (; g < nGroups; g += stride) {
      const float* s; unsigned short* d; long j;
      if (g < GX) { s = x; d = xb; j = g; }
      else { s = w1; d = w1b; j = g - GX; }
      long e8 = j * 8;
      float4 v0 = *(const float4*)(s + e8);
      float4 v1 = *(const float4*)(s + e8 + 4);
      short8 pk;
      pk[0] = (short)f2bf(v0.x); pk[1] = (short)f2bf(v0.y);
      pk[2] = (short)f2bf(v0.z); pk[3] = (short)f2bf(v0.w);
      pk[4] = (short)f2bf(v1.x); pk[5] = (short)f2bf(v1.y);
      pk[6] = (short)f2bf(v1.z); pk[7] = (short)f2bf(v1.w);
      *(short8*)(d + e8) = pk;
    }
  }
}

// single block: register histogram -> wave reduce -> LDS combine -> poff prefix
__global__ __launch_bounds__(1024) void count_k(const int* __restrict__ eids,
                                                int* __restrict__ poff) {
  __shared__ int hist[16][EN];
  int tid = threadIdx.x, lane = tid & 63, w = tid >> 6;
  int c[EN];
#pragma unroll
  for (int e = 0; e < EN; ++e) c[e] = 0;
  for (int i = tid; i < 2 * TN; i += 1024) {
    int e = eids[i];
#pragma unroll
    for (int j = 0; j < EN; ++j) c[j] += (e == j) ? 1 : 0;
  }
#pragma unroll
  for (int j = 0; j < EN; ++j) {
#pragma unroll
    for (int off = 32; off > 0; off >>= 1) c[j] += __shfl_xor(c[j], off);
  }
  if (lane == 0) {
#pragma unroll
    for (int j = 0; j < EN; ++j) hist[w][j] = c[j];
  }
  __syncthreads();
  if (tid == 0) {
    int o = 0;
    for (int e = 0; e < EN; ++e) {
      int s = 0;
      for (int ww = 0; ww < 16; ++ww) s += hist[ww][e];
      poff[e] = o;
      o += (s + 127) & ~127;
    }
    poff[EN] = o;
  }
}

__global__ __launch_bounds__(256) void scatter_k(const int* __restrict__ eids,
                                                 const float* __restrict__ wts,
                                                 const int* __restrict__ poff,
                                                 int* __restrict__ cursor,
                                                 int* __restrict__ pairTok,
                                                 float* __restrict__ pairW,
                                                 int* __restrict__ slotPos) {
  int t = blockIdx.x * 256 + threadIdx.x;
#pragma unroll
  for (int k = 0; k < 2; ++k) {
    int e = eids[2 * t + k];
    int p = atomicAdd(&cursor[e], 1);
    int pos = poff[e] + p;
    pairTok[pos] = t;
    pairW[pos] = wts[2 * t + k];
    slotPos[2 * t + k] = pos;
  }
}

// out[t] = w0 * yb[pos0] + w1 * yb[pos1]   (single-plane yb)
__global__ __launch_bounds__(256) void combine_k(const unsigned short* __restrict__ yb,
                                                 const float* __restrict__ wts,
                                                 const int* __restrict__ slotPos,
                                                 float* __restrict__ out) {
  int t = blockIdx.x;
  int p0 = slotPos[2 * t], p1 = slotPos[2 * t + 1];
  float w0 = wts[2 * t], w1 = wts[2 * t + 1];
  int c = threadIdx.x * 4;
  ushort4v y0 = *(const ushort4v*)(yb + (long)p0 * DN + c);
  ushort4v y1 = *(const ushort4v*)(yb + (long)p1 * DN + c);
  float4 o;
  o.x = w0 * bf2f(y0.x) + w1 * bf2f(y1.x);
  o.y = w0 * bf2f(y0.y) + w1 * bf2f(y1.y);
  o.z = w0 * bf2f(y0.z) + w1 * bf2f(y1.z);
  o.w = w0 * bf2f(y0.w) + w1 * bf2f(y1.w);
  *(float4*)(out + (long)t * DN + c) = o;
}

// split-K dense: out[t] = w0*(ybA[p0]+ybB[p0]) + w1*(ybA[p1]+ybB[p1])
__global__ __launch_bounds__(256) void combine2_k(const unsigned short* __restrict__ yb,
                                                  const float* __restrict__ wts,
                                                  const int* __restrict__ slotPos,
                                                  float* __restrict__ out) {
  const long H = (long)PADMAX * DN;
  int t = blockIdx.x;
  int p0 = slotPos[2 * t], p1 = slotPos[2 * t + 1];
  float w0 = wts[2 * t], w1 = wts[2 * t + 1];
  int c = threadIdx.x * 4;
  ushort4v a0 = *(const ushort4v*)(yb + (long)p0 * DN + c);
  ushort4v b0 = *(const ushort4v*)(yb + H + (long)p0 * DN + c);
  ushort4v a1 = *(const ushort4v*)(yb + (long)p1 * DN + c);
  ushort4v b1 = *(const ushort4v*)(yb + H + (long)p1 * DN + c);
  float4 o;
  o.x = w0 * (bf2f(a0.x) + bf2f(b0.x)) + w1 * (bf2f(a1.x) + bf2f(b1.x));
  o.y = w0 * (bf2f(a0.y) + bf2f(b0.y)) + w1 * (bf2f(a1.y) + bf2f(b1.y));
  o.z = w0 * (bf2f(a0.z) + bf2f(b0.z)) + w1 * (bf2f(a1.z) + bf2f(b1.z));
  o.w = w0 * (bf2f(a0.w) + bf2f(b0.w)) + w1 * (bf2f(a1.w) + bf2f(b1.w));
  *(float4*)(out + (long)t * DN + c) = o;
}

// ---- 128x128 GEMM, BK=64, 4 waves (2x2), 64 KiB LDS dbuf -> 2 blocks/CU ----
// MODE 1: fc1 h=gelu(...); z=1 plane converts w2 fp32->bf16 (overlapped)
// MODE 2: fc2 single-z dense
// MODE 4: fc2 split-K=2 dense (z halves K; z-planes of yb; combine2 sums)
//         R15: fixes fc2's 1152-block/2.25-round 75% tail -> 2304/4.5 = 90%.
// MODE 3: fallback atomics with split-K 2

#define BAR() { asm volatile("" ::: "memory"); __builtin_amdgcn_s_barrier(); \
                asm volatile("" ::: "memory"); }
#define LGKM0() { asm volatile("s_waitcnt lgkmcnt(0)" ::: "memory"); }

#define LDA4(PAR) { const char* _b = smem + (PAR)*16384;                             \
  _Pragma("unroll") for (int m = 0; m < 4; ++m) {                                    \
    int row = waveM*64 + m*16 + (lane & 15); int cb = row * 128;                     \
    a[m][0] = *(const short8*)(_b + cb + (((lane>>4) ^ (row&7)) * 16));              \
    a[m][1] = *(const short8*)(_b + cb + (((4 + (lane>>4)) ^ (row&7)) * 16)); } }

#define LDB2(NH, PAR) { const char* _b = smem + 32768 + (PAR)*16384;                 \
  _Pragma("unroll") for (int n = 0; n < 2; ++n) {                                    \
    int row = waveN*64 + ((NH)*2+n)*16 + (lane & 15); int cb = row * 128;            \
    b[(NH)*2+n][0] = *(const short8*)(_b + cb + (((lane>>4) ^ (row&7)) * 16));       \
    b[(NH)*2+n][1] = *(const short8*)(_b + cb + (((4 + (lane>>4)) ^ (row&7)) * 16)); } }

#define MM16(NH) { __builtin_amdgcn_s_setprio(1);                                    \
  _Pragma("unroll") for (int m = 0; m < 4; ++m)                                      \
    _Pragma("unroll") for (int n = 0; n < 2; ++n) {                                  \
      acc[m][(NH)*2+n] = __builtin_amdgcn_mfma_f32_16x16x32_bf16(                    \
          a[m][0], b[(NH)*2+n][0], acc[m][(NH)*2+n], 0, 0, 0);                       \
      acc[m][(NH)*2+n] = __builtin_amdgcn_mfma_f32_16x16x32_bf16(                    \
          a[m][1], b[(NH)*2+n][1], acc[m][(NH)*2+n], 0, 0, 0); }                     \
  __builtin_amdgcn_s_setprio(0); }

template <int MODE, bool BBF16>
__global__ __launch_bounds__(256, 2) void moe_gemm128_k(
    const unsigned short* __restrict__ Ab, const void* __restrict__ Bsrc,
    void* __restrict__ OutP, const int* __restrict__ pairTok,
    const float* __restrict__ pairW, const int* __restrict__ poff, int chunkStart,
    const float* __restrict__ w2src, unsigned short* __restrict__ w2dst) {
  constexpr int KD = (MODE == 1) ? DN : HN;
  constexpr int ND = (MODE == 1) ? HN : DN;
  constexpr int SPLIT = (MODE == 3 || MODE == 4) ? 2 : 1;
  constexpr int KLEN = KD / SPLIT;
  constexpr int NT = KLEN / 64;

  extern __shared__ char smem[];

  if (MODE == 1 && blockIdx.z == 1) {
    // helper blocks: grid-stride w2 fp32->bf16 cvt, overlapped with fc1 GEMM
    const long nG = (long)EN * HN * DN / 8;
    long b = (long)blockIdx.y * gridDim.x + blockIdx.x;
    long g = b * 256 + threadIdx.x;
    long stride = (long)gridDim.x * gridDim.y * 256;
    for (; g < nG; g += stride) {
      long e8 = g * 8;
      float4 v0 = *(const float4*)(w2src + e8);
      float4 v1 = *(const float4*)(w2src + e8 + 4);
      short8 pk;
      pk[0] = (short)f2bf(v0.x); pk[1] = (short)f2bf(v0.y);
      pk[2] = (short)f2bf(v0.z); pk[3] = (short)f2bf(v0.w);
      pk[4] = (short)f2bf(v1.x); pk[5] = (short)f2bf(v1.y);
      pk[6] = (short)f2bf(v1.z); pk[7] = (short)f2bf(v1.w);
      *(short8*)(w2dst + e8) = pk;
    }
    return;
  }

  int NX = gridDim.x;
  int NXY = NX * gridDim.y;
  int orig = blockIdx.y * NX + blockIdx.x;
  int qq = NXY >> 3, rrm = NXY & 7;
  int xcd = orig & 7, pos = orig >> 3;
  int wg = (xcd < rrm ? xcd * (qq + 1) : rrm * (qq + 1) + (xcd - rrm) * qq) + pos;

  int NYt = NXY / NX;
  const int GH = 8;
  int npg = GH * NX;
  int gid = wg / npg;
  int rem = wg - gid * npg;
  int rowsLeft = NYt - gid * GH;
  int gh = rowsLeft < GH ? rowsLeft : GH;
  int row = gid * GH + rem % gh;
  int col = rem / gh;
  int tileN = col * 128;
  int tileStart = chunkStart + row * 128;

  int Ppad = poff[EN];
  if (tileStart >= Ppad) return;
  int e = 0;
  while (e < EN - 1 && tileStart >= poff[e + 1]) ++e;

  int tid = threadIdx.x;
  int wid = tid >> 6, lane = tid & 63;
  int waveM = wid >> 1, waveN = wid & 1;
  int kbase = (MODE >= 3) ? blockIdx.z * KLEN : 0;

  int r0 = tid >> 3;
  const char* aSrc[4];
  const char* bSrc[4];
#pragma unroll
  for (int j = 0; j < 4; ++j) {
    int rw_ = j * 32 + r0;
    int s = (tid & 7) ^ (rw_ & 7);
    long abase;
    if (MODE == 1) {
      int tok = pairTok[tileStart + rw_];
      if (tok < 0) tok = 0;  // padding row: load token 0, result never read
      abase = (long)tok * KD;
    } else {
      abase = (long)(tileStart - chunkStart + rw_) * KD;
    }
    aSrc[j] = (const char*)(Ab + abase + kbase + s * 8);
    long bb = (long)e * ND * KD + (long)(tileN + rw_) * KD + kbase + s * 8;
    bSrc[j] = (const char*)Bsrc + bb * (BBF16 ? 2 : 4);
  }

  auto stageA = [&](int k0, int par) {
#pragma unroll
    for (int j = 0; j < 4; ++j)
      gload_lds16(aSrc[j] + (long)k0 * 2, smem + par * 16384 + (j * 256 + tid) * 16);
  };
  auto stageB = [&](int k0, int par) {
    if constexpr (BBF16) {
#pragma unroll
      for (int j = 0; j < 4; ++j)
        gload_lds16(bSrc[j] + (long)k0 * 2, smem + 32768 + par * 16384 + (j * 256 + tid) * 16);
    } else {
#pragma unroll
      for (int j = 0; j < 4; ++j) {
        const float4* pf = (const float4*)(bSrc[j] + (long)k0 * 4);
        float4 v0 = pf[0], v1 = pf[1];
        short8 pk;
        pk[0] = (short)f2bf(v0.x); pk[1] = (short)f2bf(v0.y);
        pk[2] = (short)f2bf(v0.z); pk[3] = (short)f2bf(v0.w);
        pk[4] = (short)f2bf(v1.x); pk[5] = (short)f2bf(v1.y);
        pk[6] = (short)f2bf(v1.z); pk[7] = (short)f2bf(v1.w);
        *(short8*)(smem + 32768 + par * 16384 + (j * 256 + tid) * 16) = pk;
      }
    }
  };

  f32x4 acc[4][4];
#pragma unroll
  for (int m = 0; m < 4; ++m)
#pragma unroll
    for (int n = 0; n < 4; ++n) acc[m][n] = (f32x4){0.f, 0.f, 0.f, 0.f};
  short8 a[4][2], b[4][2];

  stageA(0, 0); stageB(0, 0);
  stageA(64, 1); stageB(64, 1);
  if constexpr (BBF16) {
    asm volatile("s_waitcnt vmcnt(8)" ::: "memory");
  } else {
    asm volatile("s_waitcnt vmcnt(0) lgkmcnt(0)" ::: "memory");
  }
  BAR();

  for (int t = 0; t < NT; ++t) {
    int P = t & 1;
    int k2 = (t + 2) * 64;
    LDA4(P); LDB2(0, P);
    BAR(); LGKM0();
    MM16(0);
    BAR();
    LDB2(1, P);
    if (t + 2 < NT) stageA(k2, P);
    BAR(); LGKM0();
    MM16(1);
    if (t + 2 < NT) stageB(k2, P);
    if (BBF16 && t + 2 < NT) {
      asm volatile("s_waitcnt vmcnt(8)" ::: "memory");
    } else {
      asm volatile("s_waitcnt vmcnt(0)" ::: "memory");
    }
    BAR();
  }

  if (MODE == 1) {
    unsigned short* hbp = (unsigned short*)OutP;
    int rl0 = tileStart - chunkStart + waveM * 64;
#pragma unroll
    for (int m = 0; m < 4; ++m) {
#pragma unroll
      for (int r = 0; r < 4; ++r) {
        int rl = rl0 + m * 16 + (lane >> 4) * 4 + r;
#pragma unroll
        for (int n = 0; n < 4; ++n) {
          int coln = tileN + waveN * 64 + n * 16 + (lane & 15);
          hbp[(long)rl * HN + coln] = f2bf(gelu_f(acc[m][n][r]));
        }
      }
    }
  } else if (MODE == 2 || MODE == 4) {
    unsigned short* ybp = (unsigned short*)OutP;
    if (MODE == 4) ybp += (long)blockIdx.z * PADMAX * DN;
#pragma unroll
    for (int m = 0; m < 4; ++m) {
#pragma unroll
      for (int r = 0; r < 4; ++r) {
        int p = tileStart + waveM * 64 + m * 16 + (lane >> 4) * 4 + r;
#pragma unroll
        for (int n = 0; n < 4; ++n) {
          int coln = tileN + waveN * 64 + n * 16 + (lane & 15);
          ybp[(long)p * ND + coln] = f2bf(acc[m][n][r]);
        }
      }
    }
  } else {
    float* outF = (float*)OutP;
#pragma unroll
    for (int m = 0; m < 4; ++m) {
#pragma unroll
      for (int r = 0; r < 4; ++r) {
        int p = tileStart + waveM * 64 + m * 16 + (lane >> 4) * 4 + r;
        int tok = pairTok[p];
        if (tok < 0) continue;
        float wv = pairW[p];
#pragma unroll
        for (int n = 0; n < 4; ++n) {
          int coln = tileN + waveN * 64 + n * 16 + (lane & 15);
          atomicAdd(&outF[(long)tok * DN + coln], wv * acc[m][n][r]);
        }
      }
    }
  }
}

extern "C" void kernel_launch(void* const* d_in, const int* in_sizes, int n_in,
                              void* d_out, int out_size, void* d_ws, size_t ws_size,
                              hipStream_t stream) {
  const float* x = (const float*)d_in[0];
  const float* rw = (const float*)d_in[1];
  const float* w1 = (const float*)d_in[2];
  const float* w2 = (const float*)d_in[3];
  char* W = (char*)d_ws;
  size_t off = 0;
  auto alloc = [&](size_t sz) {
    off = (off + 255) & ~(size_t)255;
    size_t r = off; off += sz; return r;
  };
  size_t ctrlO = alloc(256);  // cursor[8], poff[9]
  size_t eidsO = alloc((size_t)TN * 2 * 4);
  size_t wtsO  = alloc((size_t)TN * 2 * 4);
  size_t ptokO = alloc((size_t)PADMAX * 4);
  size_t pwO   = alloc((size_t)PADMAX * 4);
  size_t sposO = alloc((size_t)TN * 2 * 4);
  size_t xbO   = alloc((size_t)TN * DN * 2);
  size_t wB = (size_t)EN * HN * DN * 2;
  size_t afterFixed = (off + 255) & ~(size_t)255;
  size_t hbNeed = (size_t)128 * HN * 2 + 4096;
  bool bw = ws_size >= afterFixed + 2 * wB + hbNeed;
  size_t w1bO = 0, w2bO = 0;
  if (bw) { w1bO = alloc(wB); w2bO = alloc(wB); }
  size_t ybB = (size_t)PADMAX * DN * 2;
  size_t afterW = (off + 255) & ~(size_t)255;
  bool dense2 = ws_size >= afterW + 2 * ybB + hbNeed;
  bool dense  = dense2 || ws_size >= afterW + ybB + hbNeed;
  size_t ybO = 0;
  if (dense2) ybO = alloc(2 * ybB);
  else if (dense) ybO = alloc(ybB);
  size_t hbase = (off + 255) & ~(size_t)255;
  size_t avail = ws_size > hbase ? ws_size - hbase : (size_t)128 * HN * 2;
  long Cl = (long)(avail / ((size_t)HN * 2));
  if (Cl > PADMAX) Cl = PADMAX;
  Cl &= ~127l;
  if (Cl < 128) Cl = 128;
  int C = (int)Cl;
  size_t hbO = alloc((size_t)C * HN * 2);
  int nCh = (PADMAX + C - 1) / C;

  int* cursor = (int*)(W + ctrlO);
  int* poff = cursor + 8;
  int* eids = (int*)(W + eidsO);
  float* wts = (float*)(W + wtsO);
  int* pairTok = (int*)(W + ptokO);
  float* pairW = (float*)(W + pwO);
  int* slotPos = (int*)(W + sposO);
  unsigned short* xb = (unsigned short*)(W + xbO);
  unsigned short* hb = (unsigned short*)(W + hbO);
  unsigned short* yb = (unsigned short*)(W + ybO);

  hipFuncSetAttribute(reinterpret_cast<const void*>(moe_gemm128_k<1, true>),
                      hipFuncAttributeMaxDynamicSharedMemorySize, 65536);
  hipFuncSetAttribute(reinterpret_cast<const void*>(moe_gemm128_k<2, true>),
                      hipFuncAttributeMaxDynamicSharedMemorySize, 65536);
  hipFuncSetAttribute(reinterpret_cast<const void*>(moe_gemm128_k<3, true>),
                      hipFuncAttributeMaxDynamicSharedMemorySize, 65536);
  hipFuncSetAttribute(reinterpret_cast<const void*>(moe_gemm128_k<4, true>),
                      hipFuncAttributeMaxDynamicSharedMemorySize, 65536);
  hipFuncSetAttribute(reinterpret_cast<const void*>(moe_gemm128_k<1, false>),
                      hipFuncAttributeMaxDynamicSharedMemorySize, 65536);
  hipFuncSetAttribute(reinterpret_cast<const void*>(moe_gemm128_k<2, false>),
                      hipFuncAttributeMaxDynamicSharedMemorySize, 65536);
  hipFuncSetAttribute(reinterpret_cast<const void*>(moe_gemm128_k<3, false>),
                      hipFuncAttributeMaxDynamicSharedMemorySize, 65536);
  hipFuncSetAttribute(reinterpret_cast<const void*>(moe_gemm128_k<4, false>),
                      hipFuncAttributeMaxDynamicSharedMemorySize, 65536);

  hipMemsetAsync(W + ctrlO, 0, 256, stream);
  hipMemsetAsync(W + ptokO, 0xFF, (size_t)PADMAX * 4, stream);  // pairTok = -1
  if (!dense) hipMemsetAsync(d_out, 0, (size_t)TN * DN * 4, stream);

  const int nCvtBlk = 4096;
  const long GX = (long)TN * DN / 8;
  const long GW = (long)EN * HN * DN / 8;
  long nGroups = GX + (bw ? GW : 0);  // x + w1 only
  prep_k<<<TN / 4 + nCvtBlk, 256, 0, stream>>>(
      x, rw, w1, xb,
      bw ? (unsigned short*)(W + w1bO) : nullptr,
      eids, wts, nCvtBlk, nGroups);
  count_k<<<1, 1024, 0, stream>>>(eids, poff);
  scatter_k<<<TN / 256, 256, 0, stream>>>(eids, wts, poff, cursor, pairTok, pairW, slotPos);

  int Ctiles = C / 128;
  for (int c = 0; c < nCh; ++c) {
    int cs = c * C;
    if (bw) {
      // z=0: fc1 GEMM; z=1 (first chunk only): w2 cvt overlapped
      moe_gemm128_k<1, true><<<dim3(HN / 128, Ctiles, c == 0 ? 2 : 1), 256, 65536, stream>>>(
          xb, W + w1bO, hb, pairTok, pairW, poff, cs, w2,
          (unsigned short*)(W + w2bO));
      if (dense2) {
        moe_gemm128_k<4, true><<<dim3(DN / 128, Ctiles, 2), 256, 65536, stream>>>(
            hb, W + w2bO, yb, pairTok, pairW, poff, cs, nullptr, nullptr);
      } else if (dense) {
        moe_gemm128_k<2, true><<<dim3(DN / 128, Ctiles, 1), 256, 65536, stream>>>(
            hb, W + w2bO, yb, pairTok, pairW, poff, cs, nullptr, nullptr);
      } else {
        moe_gemm128_k<3, true><<<dim3(DN / 128, Ctiles, 2), 256, 65536, stream>>>(
            hb, W + w2bO, d_out, pairTok, pairW, poff, cs, nullptr, nullptr);
      }
    } else {
      moe_gemm128_k<1, false><<<dim3(HN / 128, Ctiles, 1), 256, 65536, stream>>>(
          xb, w1, hb, pairTok, pairW, poff, cs, nullptr, nullptr);
      if (dense2) {
        moe_gemm128_k<4, false><<<dim3(DN / 128, Ctiles, 2), 256, 65536, stream>>>(
            hb, w2, yb, pairTok, pairW, poff, cs, nullptr, nullptr);
      } else if (dense) {
        moe_gemm128_k<2, false><<<dim3(DN / 128, Ctiles, 1), 256, 65536, stream>>>(
            hb, w2, yb, pairTok, pairW, poff, cs, nullptr, nullptr);
      } else {
        moe_gemm128_k<3, false><<<dim3(DN / 128, Ctiles, 2), 256, 65536, stream>>>(
            hb, w2, d_out, pairTok, pairW, poff, cs, nullptr, nullptr);
      }
    }
  }
  if (dense2) {
    combine2_k<<<TN, 256, 0, stream>>>(yb, wts, slotPos, (float*)d_out);
  } else if (dense) {
    combine_k<<<TN, 256, 0, stream>>>(yb, wts, slotPos, (float*)d_out);
  }
}